// Round 1
// baseline (344.797 us; speedup 1.0000x reference)
//
#include <hip/hip_runtime.h>
#include <cstdint>

#define NPOS   32768   // B*H*W
#define KCODE  1024
#define DDIM   256
#define NT     64      // positions per block
#define KCHUNK 128
#define DCHUNK 16
#define BSROW  132     // padded k-row for Bs (+4 floats keeps 16B align, breaks write conflicts)

// ---- kernel 0: wsq[k] = sum_d w[k][d]^2 ------------------------------------
__global__ void wsq_kernel(const float* __restrict__ w, float* __restrict__ wsq) {
  const int k = blockIdx.x;       // 1024
  const int lane = threadIdx.x;   // 64
  float4 v = *(const float4*)(w + (size_t)k * DDIM + lane * 4);
  float s = v.x * v.x + v.y * v.y + v.z * v.z + v.w * v.w;
  #pragma unroll
  for (int off = 32; off > 0; off >>= 1) s += __shfl_down(s, off, 64);
  if (lane == 0) wsq[k] = s;
}

// ---- kernel 1: fused dist-GEMM + argmin ------------------------------------
// dist(n,k) = wsq[k] - 2 * x_n . w_k   (+||x||^2 is constant per n, irrelevant)
__global__ __launch_bounds__(256) void argmin_kernel(
    const float* __restrict__ z, const float* __restrict__ w,
    const float* __restrict__ wsq, int* __restrict__ idxout) {
  // As [256 d][64 n] = 64KB, reused as reduction scratch after the k-loop
  __shared__ __align__(16) char smem_raw[DDIM * NT * 4];
  __shared__ __align__(16) float Bs[DCHUNK * BSROW];   // [dd][k] transposed chunk
  float* As = (float*)smem_raw;
  unsigned long long* Red = (unsigned long long*)smem_raw;

  const int tid = threadIdx.x;
  const int n0 = blockIdx.x * NT;        // 512 blocks
  const int b = n0 >> 10;                // 1024 positions per image
  const int hw0 = n0 & 1023;
  const float* zb = z + ((size_t)b * DDIM) * 1024 + hw0;

  // stage full A tile: As[d][i] = z[b][d][hw0+i], coalesced f4 loads
  {
    const int drow = tid >> 4;
    const int i4 = tid & 15;
    #pragma unroll
    for (int p = 0; p < 16; ++p) {
      const int d = p * 16 + drow;
      float4 v = *(const float4*)(zb + (size_t)d * 1024 + i4 * 4);
      *(float4*)(As + d * NT + i4 * 4) = v;
    }
  }

  const int tx = tid & 31;  // 32 groups x 4 k
  const int ty = tid >> 5;  // 8 groups x 8 n

  unsigned long long best[8];
  #pragma unroll
  for (int r = 0; r < 8; ++r) best[r] = ~0ull;

  for (int kc = 0; kc < KCODE / KCHUNK; ++kc) {
    const int k0 = kc * KCHUNK;
    float acc[8][4];
    #pragma unroll
    for (int r = 0; r < 8; ++r)
      #pragma unroll
      for (int j = 0; j < 4; ++j) acc[r][j] = 0.f;

    for (int dc = 0; dc < DDIM / DCHUNK; ++dc) {
      __syncthreads();
      // stage Bs chunk: w[k0..k0+128)[dc*16..+16), transposed to [d][k]
      #pragma unroll
      for (int q = 0; q < 2; ++q) {
        const int f = q * 256 + tid;
        const int kl = f >> 2;     // 0..127
        const int dj4 = f & 3;     // 0..3 (f4 within the 16-d slice)
        float4 v = *(const float4*)(w + (size_t)(k0 + kl) * DDIM + dc * DCHUNK + dj4 * 4);
        Bs[(dj4 * 4 + 0) * BSROW + kl] = v.x;
        Bs[(dj4 * 4 + 1) * BSROW + kl] = v.y;
        Bs[(dj4 * 4 + 2) * BSROW + kl] = v.z;
        Bs[(dj4 * 4 + 3) * BSROW + kl] = v.w;
      }
      __syncthreads();
      #pragma unroll
      for (int dd = 0; dd < DCHUNK; ++dd) {
        const int d = dc * DCHUNK + dd;
        float4 a0 = *(const float4*)(As + d * NT + ty * 8);
        float4 a1 = *(const float4*)(As + d * NT + ty * 8 + 4);
        float4 bv = *(const float4*)(Bs + dd * BSROW + tx * 4);
        const float a[8] = {a0.x, a0.y, a0.z, a0.w, a1.x, a1.y, a1.z, a1.w};
        const float bb[4] = {bv.x, bv.y, bv.z, bv.w};
        #pragma unroll
        for (int r = 0; r < 8; ++r)
          #pragma unroll
          for (int j = 0; j < 4; ++j) acc[r][j] += a[r] * bb[j];
      }
    }

    // fold this k-chunk into the running argmin (packed monotone key | k)
    float4 wq4 = *(const float4*)(wsq + k0 + tx * 4);
    const float wq[4] = {wq4.x, wq4.y, wq4.z, wq4.w};
    #pragma unroll
    for (int r = 0; r < 8; ++r) {
      #pragma unroll
      for (int j = 0; j < 4; ++j) {
        float dist = wq[j] - 2.0f * acc[r][j];
        unsigned u = __float_as_uint(dist);
        u = (u & 0x80000000u) ? ~u : (u | 0x80000000u);  // monotone total order
        unsigned long long key =
            ((unsigned long long)u << 32) | (unsigned)(k0 + tx * 4 + j);
        best[r] = best[r] < key ? best[r] : key;         // ties -> smallest k
      }
    }
  }

  // cross-thread reduction: 32 tx-threads per n-row
  __syncthreads();
  #pragma unroll
  for (int r = 0; r < 8; ++r) Red[(ty * 8 + r) * 33 + tx] = best[r];
  __syncthreads();
  if (tid < NT) {
    unsigned long long m = Red[tid * 33];
    for (int i = 1; i < 32; ++i) {
      unsigned long long v = Red[tid * 33 + i];
      m = v < m ? v : m;
    }
    idxout[n0 + tid] = (int)(m & 0xFFFFFFFFull);
  }
}

// ---- kernel 2: gather + permute-back, writes both outputs ------------------
__global__ void gather_kernel(const float* __restrict__ w, const int* __restrict__ idx,
                              float* __restrict__ out) {
  const int g = blockIdx.x * 256 + threadIdx.x;  // [0, 2097152) float4s
  const int hw4 = g & 255;
  const int c = (g >> 8) & 255;
  const int b = g >> 16;
  int4 kv = *(const int4*)(idx + b * 1024 + hw4 * 4);
  float4 v;
  v.x = w[(size_t)kv.x * 256 + c];
  v.y = w[(size_t)kv.y * 256 + c];
  v.z = w[(size_t)kv.z * 256 + c];
  v.w = w[(size_t)kv.w * 256 + c];
  float4* o = (float4*)out;
  o[g] = v;              // codes
  o[g + 2097152] = v;    // codes_bar (identical forward value)
}

extern "C" void kernel_launch(void* const* d_in, const int* in_sizes, int n_in,
                              void* d_out, int out_size, void* d_ws, size_t ws_size,
                              hipStream_t stream) {
  const float* z = (const float*)d_in[0];   // [32,256,32,32] fp32
  const float* w = (const float*)d_in[1];   // [1024,256] fp32
  float* wsq = (float*)d_ws;                              // 4KB
  int* idx = (int*)((char*)d_ws + 4096);                  // 128KB
  float* out = (float*)d_out;

  wsq_kernel<<<KCODE, 64, 0, stream>>>(w, wsq);
  argmin_kernel<<<NPOS / NT, 256, 0, stream>>>(z, w, wsq, idx);
  gather_kernel<<<2097152 / 256, 256, 0, stream>>>(w, idx, out);
}